// Round 3
// baseline (271.434 us; speedup 1.0000x reference)
//
#include <hip/hip_runtime.h>
#include <stdint.h>

typedef unsigned short u16;
typedef __bf16 bf16x8 __attribute__((ext_vector_type(8)));
typedef float  f32x4  __attribute__((ext_vector_type(4)));

#define B_  2
#define T_  1024
#define C_  2048
#define H_  16
#define D_  128
#define NTENS 4194304   // elements in x and in each W (2*1024*2048 == 2048*2048)

__device__ __forceinline__ u16 f2bf(float f) {
    union { float f; uint32_t u; } v; v.f = f;
    uint32_t r = (v.u + 0x7FFFu + ((v.u >> 16) & 1u)) >> 16;
    return (u16)r;
}
__device__ __forceinline__ float bf2f(u16 h) {
    union { uint32_t u; float f; } v; v.u = ((uint32_t)h) << 16;
    return v.f;
}

// ---------------------------------------------------------------------------
// fp32 -> bf16 conversion; z in [0,5): {x,Wq,Wk,Wv,Wo}. z==5: RoPE table
// (first 64 blocks only) — folded here to save a launch.
// ---------------------------------------------------------------------------
__global__ __launch_bounds__(256) void k_convert(
    const float* __restrict__ x, const float* __restrict__ wq,
    const float* __restrict__ wk, const float* __restrict__ wv,
    const float* __restrict__ wo, u16* __restrict__ dst,
    float* __restrict__ ct, float* __restrict__ st)
{
    int z = blockIdx.z;
    if (z == 5) {
        int idx = blockIdx.x * 256 + threadIdx.x;
        if (idx < 65536) {
            int t = idx >> 6, d = idx & 63;
            float inv = expf(-(float)d * (9.210340371976184f / 64.0f));
            float th = (float)t * inv;
            float s, c;
            sincosf(th, &s, &c);
            ct[idx] = c;
            st[idx] = s;
        }
        return;
    }
    const float* src = (z == 0) ? x : (z == 1) ? wq : (z == 2) ? wk : (z == 3) ? wv : wo;
    u16* d = dst + (size_t)z * NTENS;
    size_t i = ((size_t)blockIdx.x * 256 + threadIdx.x) * 4;
    float4 v = *(const float4*)(src + i);
    ushort4 o;
    o.x = f2bf(v.x); o.y = f2bf(v.y); o.z = f2bf(v.z); o.w = f2bf(v.w);
    *(ushort4*)(d + i) = o;
}

// ---------------------------------------------------------------------------
// Generic NT-form MTILE x 128 tile GEMM, 1x4 waves (kept for k_gemm_out,
// MTILE=64 verified optimum for this shape).
// ---------------------------------------------------------------------------
template<int MTILE, int EPI>
__device__ __forceinline__ void gemm_tile_nt(
    const u16* __restrict__ A, int lda,
    const u16* __restrict__ Bp, int ldb,
    void* __restrict__ Cp, int ldc,
    int m0, int n0, int K, u16* SMEM)
{
    constexpr int MF  = MTILE / 16;
    constexpr int ACH = MTILE / 32;
    u16* As = SMEM;
    u16* Bs = SMEM + MTILE * 64;

    const int tid  = threadIdx.x;
    const int wave = tid >> 6;
    const int lane = tid & 63;
    const int frow = lane & 15;
    const int quad = lane >> 4;

    const int lrow8  = lane >> 3;
    const int slot   = lane & 7;
    const int gchunk = slot ^ lrow8;

    f32x4 acc[MF][2] = {};

    size_t aoff[ACH], boff[4];
#pragma unroll
    for (int i = 0; i < ACH; ++i) {
        int c = (i << 2) + wave;
        int r = (c << 3) + lrow8;
        aoff[i] = (size_t)(m0 + r) * lda + (gchunk << 3);
    }
#pragma unroll
    for (int i = 0; i < 4; ++i) {
        int r = (i << 5) + (wave << 3) + lrow8;
        boff[i] = (size_t)(n0 + r) * ldb + (gchunk << 3);
    }

    for (int kt = 0; kt < K; kt += 64) {
#pragma unroll
        for (int i = 0; i < ACH; ++i) {
            int c = (i << 2) + wave;
            __builtin_amdgcn_global_load_lds(
                (const __attribute__((address_space(1))) void*)(A + aoff[i] + kt),
                (__attribute__((address_space(3))) void*)(As + (c << 9)), 16, 0, 0);
        }
#pragma unroll
        for (int i = 0; i < 4; ++i) {
            int c = (i << 2) + wave;
            __builtin_amdgcn_global_load_lds(
                (const __attribute__((address_space(1))) void*)(Bp + boff[i] + kt),
                (__attribute__((address_space(3))) void*)(Bs + (c << 9)), 16, 0, 0);
        }
        __syncthreads();

#pragma unroll
        for (int ks = 0; ks < 2; ++ks) {
            int lk = (ks << 2) + quad;
            bf16x8 af[MF], bfv[2];
#pragma unroll
            for (int i = 0; i < MF; ++i) {
                int ar = (i << 4) + frow;
                af[i] = *(const bf16x8*)&As[ar * 64 + ((lk ^ (frow & 7)) << 3)];
            }
#pragma unroll
            for (int j = 0; j < 2; ++j) {
                int br = (wave << 4) + (j << 6) + frow;
                bfv[j] = *(const bf16x8*)&Bs[br * 64 + ((lk ^ (frow & 7)) << 3)];
            }
#pragma unroll
            for (int i = 0; i < MF; ++i)
#pragma unroll
                for (int j = 0; j < 2; ++j)
                    acc[i][j] = __builtin_amdgcn_mfma_f32_16x16x32_bf16(
                        af[i], bfv[j], acc[i][j], 0, 0, 0);
        }
        __syncthreads();
    }

#pragma unroll
    for (int i = 0; i < MF; ++i)
#pragma unroll
        for (int j = 0; j < 2; ++j)
#pragma unroll
            for (int r = 0; r < 4; ++r) {
                int m = m0 + (i << 4) + (quad << 2) + r;
                int n = n0 + (wave << 4) + (j << 6) + frow;
                if constexpr (EPI == 0)
                    ((float*)Cp)[(size_t)m * ldc + n] = acc[i][j][r];
                else
                    ((u16*)Cp)[(size_t)m * ldc + n] = f2bf(acc[i][j][r]);
            }
}

// ---------------------------------------------------------------------------
// QKV GEMM: 128x128 tile, 2x2 wave decomposition (m97 structure: each wave
// owns 64x64, per ks 8 ds_read_b128 : 16 MFMA, 32 MFMA/wave per barrier
// pair — vs round-1's failed 1x4/MF=8 shape).
// Column assignment keeps RoPE in-lane: wave wc owns 16-col groups
// {2wc, 2wc+1, 4+2wc, 4+2wc+1}, so acc[i][j] (cols 32wc+16j+frow, j<2)
// pairs with acc[i][j+2] (same +64) in-register.
// Epilogue: z<2 RoPE -> bf16 [t][c]; z==2 V fused-transpose -> vt [bh][d][t].
// ---------------------------------------------------------------------------
__device__ __forceinline__ void gemm_tile_qkv128(
    const u16* __restrict__ A, int lda,
    const u16* __restrict__ Bp, int ldb,
    u16* __restrict__ Cp, int ldc,
    int m0, int n0, int K,
    u16* SMEM, const float* __restrict__ ct, const float* __restrict__ st, int z)
{
    u16* As = SMEM;              // [128][64] chunk-swizzled
    u16* Bs = SMEM + 128 * 64;   // [128][64] chunk-swizzled

    const int tid  = threadIdx.x;
    const int wave = tid >> 6;
    const int wr   = wave >> 1;      // 0..1 row half
    const int wc   = wave & 1;       // 0..1 col half
    const int lane = tid & 63;
    const int frow = lane & 15;
    const int quad = lane >> 4;

    const int lrow8  = lane >> 3;
    const int slot   = lane & 7;
    const int gchunk = slot ^ lrow8;

    f32x4 acc[4][4] = {};

    size_t aoff[4], boff[4];
#pragma unroll
    for (int i = 0; i < 4; ++i) {
        int c = (i << 2) + wave;          // 0..15 (8-row units)
        int r = (c << 3) + lrow8;         // 0..127
        aoff[i] = (size_t)(m0 + r) * lda + (gchunk << 3);
        boff[i] = (size_t)(n0 + r) * ldb + (gchunk << 3);
    }

    for (int kt = 0; kt < K; kt += 64) {
#pragma unroll
        for (int i = 0; i < 4; ++i) {
            int c = (i << 2) + wave;
            __builtin_amdgcn_global_load_lds(
                (const __attribute__((address_space(1))) void*)(A + aoff[i] + kt),
                (__attribute__((address_space(3))) void*)(As + (c << 9)), 16, 0, 0);
            __builtin_amdgcn_global_load_lds(
                (const __attribute__((address_space(1))) void*)(Bp + boff[i] + kt),
                (__attribute__((address_space(3))) void*)(Bs + (c << 9)), 16, 0, 0);
        }
        __syncthreads();

#pragma unroll
        for (int ks = 0; ks < 2; ++ks) {
            int lk = (ks << 2) + quad;
            int sw = (lk ^ (frow & 7)) << 3;   // row bases are %8==0 -> shared
            bf16x8 af[4], bfv[4];
#pragma unroll
            for (int i = 0; i < 4; ++i) {
                int ar = (wr << 6) + (i << 4) + frow;
                af[i] = *(const bf16x8*)&As[ar * 64 + sw];
            }
#pragma unroll
            for (int j = 0; j < 4; ++j) {
                int g = (j < 2) ? ((wc << 1) + j) : (4 + (wc << 1) + (j - 2));
                int br = (g << 4) + frow;
                bfv[j] = *(const bf16x8*)&Bs[br * 64 + sw];
            }
#pragma unroll
            for (int i = 0; i < 4; ++i)
#pragma unroll
                for (int j = 0; j < 4; ++j)
                    acc[i][j] = __builtin_amdgcn_mfma_f32_16x16x32_bf16(
                        af[i], bfv[j], acc[i][j], 0, 0, 0);
        }
        __syncthreads();
    }

    if (z < 2) {
        // RoPE epilogue: d = 32wc+16j+frow (j<2), partner d+64 = acc[i][j+2]
        const float sc = (z == 0) ? 0.08838834764831845f : 1.0f;
#pragma unroll
        for (int i = 0; i < 4; ++i)
#pragma unroll
            for (int j = 0; j < 2; ++j) {
                int d = ((wc << 1) + j) * 16 + frow;     // 0..63
#pragma unroll
                for (int r = 0; r < 4; ++r) {
                    int m = m0 + (wr << 6) + (i << 4) + (quad << 2) + r;
                    int t = m & 1023;
                    float c = ct[t * 64 + d], s = st[t * 64 + d];
                    float a = acc[i][j][r], bb = acc[i][j + 2][r];
                    Cp[(size_t)m * ldc + n0 + d]      = f2bf((a * c - bb * s) * sc);
                    Cp[(size_t)m * ldc + n0 + d + 64] = f2bf((bb * c + a * s) * sc);
                }
            }
        return;
    }
    // V fused transpose: Cp is vt [bh][d][t]; tile n-range == head n0>>7.
    const int hh = n0 >> 7;
    const int bI = m0 >> 10;                 // 128-row tiles never straddle b
    const int t0 = m0 & 1023;
    u16* Vp = Cp + ((size_t)((bI << 4) + hh)) * (D_ * T_);
#pragma unroll
    for (int i = 0; i < 4; ++i)
#pragma unroll
        for (int j = 0; j < 4; ++j) {
            int g = (j < 2) ? ((wc << 1) + j) : (4 + (wc << 1) + (j - 2));
            int d = (g << 4) + frow;
            int t = t0 + (wr << 6) + (i << 4) + (quad << 2);
            ushort4 o;
            o.x = f2bf(acc[i][j][0]); o.y = f2bf(acc[i][j][1]);
            o.z = f2bf(acc[i][j][2]); o.w = f2bf(acc[i][j][3]);
            *(ushort4*)&Vp[(size_t)d * T_ + t] = o;
        }
}

// ---------------------------------------------------------------------------
// QKV projection: 128x128 tiles, 2x2 waves. Grid (16,16,3) = 768 = 3 blk/CU.
// ---------------------------------------------------------------------------
__global__ __launch_bounds__(256) void k_gemm_qkv(
    const u16* __restrict__ xb, const u16* __restrict__ wq,
    const u16* __restrict__ wk, const u16* __restrict__ wv,
    u16* __restrict__ q, u16* __restrict__ k, u16* __restrict__ vt,
    const float* __restrict__ ct, const float* __restrict__ st)
{
    __shared__ u16 SMEM[128 * 64 + 128 * 64];
    int z = blockIdx.z;
    const u16* Bp = (z == 0) ? wq : (z == 1) ? wk : wv;
    u16* Op       = (z == 0) ? q  : (z == 1) ? k  : vt;
    gemm_tile_qkv128(xb, C_, Bp, C_, Op, C_,
                     blockIdx.y * 128, blockIdx.x * 128, C_, SMEM, ct, st, z);
}

// ---------------------------------------------------------------------------
// Fused flash attention v3: KV-tile 128, Q in registers, BOTH K and V^T
// staged with global_load_lds (V produced pre-transposed by the QKV GEMM
// epilogue). Grid 512, LPT pairing (pairs sum 9).
// LDS 64 KB: Ks[128x128] (reused as P, stride 136), Vs[128x128] ([d][tok]).
// ---------------------------------------------------------------------------
__global__ __launch_bounds__(256) void k_flash(
    const u16* __restrict__ qb, const u16* __restrict__ kb,
    const u16* __restrict__ vt, u16* __restrict__ yb)
{
    __shared__ u16 Ks[128 * 128];   // [tok][d]; P (stride 136) reuses this
    __shared__ u16 Vs[128 * 128];   // [d][tok]

    const int bx  = blockIdx.x;
    const int bh  = bx & 31, b = bh >> 4, h = bh & 15;
    const int qt  = (bx < 256) ? (15 - (bx >> 5)) : ((bx >> 5) - 8);
    const int KT  = (qt >> 1) + 1;
    const int tid = threadIdx.x, wave = tid >> 6, lane = tid & 63;
    const int frow = lane & 15, quad = lane >> 4;

    const u16* qbase = qb + (size_t)b * (T_ * C_) + h * D_;
    const u16* kbase = kb + (size_t)b * (T_ * C_) + h * D_;
    const u16* vbase = vt + (size_t)bh * (D_ * T_);
    const int q0 = qt << 6;

    // ---- Q fragments in registers (wave w owns q-rows q0+16w..+15) ----
    bf16x8 qf[4];
#pragma unroll
    for (int ks = 0; ks < 4; ++ks)
        qf[ks] = *(const bf16x8*)&qbase[(size_t)(q0 + (wave << 4) + frow) * C_
                                        + (ks << 5) + (quad << 3)];

    f32x4 Y[8] = {};
    float mrow[4], lrow[4];
#pragma unroll
    for (int r = 0; r < 4; ++r) { mrow[r] = -3e38f; lrow[r] = 0.f; }

    const int tok = q0 + (wave << 4) + (quad << 2);  // + r = global q row

    for (int kt = 0; kt < KT; ++kt) {
        const int k0 = kt << 7;
        // ---- stage K tile (128 tok x 128 d) and V^T tile (128 d x 128 tok) ----
        {
            const int r4 = lane >> 4, s16 = lane & 15;
#pragma unroll
            for (int i = 0; i < 8; ++i) {
                int c = (i << 2) + wave;             // 0..31, 4 rows each
                int row = (c << 2) + r4;             // 0..127
                int g = (s16 & 8) | ((s16 & 7) ^ (row & 7));
                __builtin_amdgcn_global_load_lds(
                    (const __attribute__((address_space(1))) void*)(kbase + (size_t)(k0 + row) * C_ + (g << 3)),
                    (__attribute__((address_space(3))) void*)(Ks + (c << 9)), 16, 0, 0);
                __builtin_amdgcn_global_load_lds(
                    (const __attribute__((address_space(1))) void*)(vbase + (size_t)row * T_ + k0 + (g << 3)),
                    (__attribute__((address_space(3))) void*)(Vs + (c << 9)), 16, 0, 0);
            }
        }
        __syncthreads();   // B1: tiles staged

        // ---- S = q K^T  (wave-tile 16 x 128) ----
        f32x4 S[8] = {};
#pragma unroll
        for (int ks = 0; ks < 4; ++ks) {
            int lk = (ks << 2) + quad;
            int sw = ((lk & 8) | ((lk & 7) ^ (frow & 7))) << 3;
#pragma unroll
            for (int jj = 0; jj < 8; ++jj) {
                bf16x8 bb = *(const bf16x8*)&Ks[((jj << 4) + frow) * 128 + sw];
                S[jj] = __builtin_amdgcn_mfma_f32_16x16x32_bf16(qf[ks], bb, S[jj], 0, 0, 0);
            }
        }

        // ---- causal mask (only the last kv-tile intersects the diagonal) ----
        if (kt == KT - 1) {
#pragma unroll
            for (int jj = 0; jj < 8; ++jj) {
                int colg = k0 + (jj << 4) + frow;
#pragma unroll
                for (int r = 0; r < 4; ++r)
                    if (colg > tok + r) S[jj][r] = -1e30f;
            }
        }

        // ---- online softmax (rows live in 16-lane frow groups) ----
        float al[4];
#pragma unroll
        for (int r = 0; r < 4; ++r) {
            float tm = -3e38f;
#pragma unroll
            for (int jj = 0; jj < 8; ++jj) tm = fmaxf(tm, S[jj][r]);
#pragma unroll
            for (int off = 8; off > 0; off >>= 1) tm = fmaxf(tm, __shfl_xor(tm, off));
            float mn = fmaxf(mrow[r], tm);
            al[r] = __expf(mrow[r] - mn);
            mrow[r] = mn;
            float rs = 0.f;
#pragma unroll
            for (int jj = 0; jj < 8; ++jj) {
                float e = __expf(S[jj][r] - mn);
                S[jj][r] = e;
                rs += e;
            }
#pragma unroll
            for (int off = 8; off > 0; off >>= 1) rs += __shfl_xor(rs, off);
            lrow[r] = lrow[r] * al[r] + rs;
        }
#pragma unroll
        for (int dj = 0; dj < 8; ++dj)
#pragma unroll
            for (int r = 0; r < 4; ++r) Y[dj][r] *= al[r];

        __syncthreads();   // B2: Ks reads done -> safe to overwrite with P

        // ---- write P into Ks region (A-layout, stride 136) ----
        u16* Ps = Ks;
#pragma unroll
        for (int jj = 0; jj < 8; ++jj)
#pragma unroll
            for (int r = 0; r < 4; ++r)
                Ps[((wave << 4) + (quad << 2) + r) * 136 + (jj << 4) + frow] = f2bf(S[jj][r]);

        // ---- Y += P V ----
#pragma unroll
        for (int ks = 0; ks < 4; ++ks) {
            bf16x8 pa = *(const bf16x8*)&Ps[((wave << 4) + frow) * 136 + (ks << 5) + (quad << 3)];
            int lk = (ks << 2) + quad;
            int sw = ((lk & 8) | ((lk & 7) ^ (frow & 7))) << 3;
#pragma unroll
            for (int dj = 0; dj < 8; ++dj) {
                bf16x8 vv = *(const bf16x8*)&Vs[((dj << 4) + frow) * 128 + sw];
                Y[dj] = __builtin_amdgcn_mfma_f32_16x16x32_bf16(pa, vv, Y[dj], 0, 0, 0);
            }
        }
        __syncthreads();   // B3: PV reads done before next-iter staging
    }

    // ---- epilogue: Y /= l, store to yb [b,t,h,d] ----
    u16* ybase = yb + (size_t)b * (T_ * C_) + h * D_;
#pragma unroll
    for (int r = 0; r < 4; ++r) {
        float inv = 1.0f / lrow[r];
#pragma unroll
        for (int dj = 0; dj < 8; ++dj)
            ybase[(size_t)(tok + r) * C_ + (dj << 4) + frow] = f2bf(Y[dj][r] * inv);
    }
}

// ---------------------------------------------------------------------------
// out = y @ Wo^T, fp32 output. 64x128 tile, grid (16,32) = 512 blocks = 2/CU
// (128-row tiles here would be 256 blocks = 1 blk/CU: latency-exposed).
// ---------------------------------------------------------------------------
__global__ __launch_bounds__(256) void k_gemm_out(
    const u16* __restrict__ yb, const u16* __restrict__ wo, float* __restrict__ out)
{
    __shared__ u16 SMEM[64 * 64 + 128 * 64];
    gemm_tile_nt<64, 0>(yb, C_, wo, C_, out, C_,
                        blockIdx.y * 64, blockIdx.x * 128, C_, SMEM);
}

// ---------------------------------------------------------------------------
extern "C" void kernel_launch(void* const* d_in, const int* in_sizes, int n_in,
                              void* d_out, int out_size, void* d_ws, size_t ws_size,
                              hipStream_t stream)
{
    (void)in_sizes; (void)n_in; (void)out_size; (void)ws_size;
    const float* x  = (const float*)d_in[0];
    const float* Wq = (const float*)d_in[1];
    const float* Wk = (const float*)d_in[2];
    const float* Wv = (const float*)d_in[3];
    const float* Wo = (const float*)d_in[4];

    u16* ws  = (u16*)d_ws;
    u16* xb  = ws;
    u16* wqb = ws + (size_t)1 * NTENS;
    u16* wkb = ws + (size_t)2 * NTENS;
    u16* wvb = ws + (size_t)3 * NTENS;
    u16* wob = ws + (size_t)4 * NTENS;
    u16* qb  = ws + (size_t)5 * NTENS;
    u16* kb  = ws + (size_t)6 * NTENS;
    // slot 7 (vb) unused since V is written pre-transposed by the QKV GEMM
    u16* yb  = ws + (size_t)8 * NTENS;
    u16* vt  = ws + (size_t)9 * NTENS;         // [bh][d][t]
    float* ct = (float*)(ws + (size_t)10 * NTENS);
    float* st = ct + 65536;

    k_convert <<<dim3(4096, 1, 6), 256, 0, stream>>>(x, Wq, Wk, Wv, Wo, ws, ct, st);
    k_gemm_qkv<<<dim3(16, 16, 3), 256, 0, stream>>>(xb, wqb, wkb, wvb, qb, kb, vt, ct, st);
    k_flash   <<<dim3(512), 256, 0, stream>>>(qb, kb, vt, yb);
    k_gemm_out<<<dim3(16, 32, 1), 256, 0, stream>>>(yb, wob, (float*)d_out);
}

// Round 4
// 256.808 us; speedup vs baseline: 1.0570x; 1.0570x over previous
//
#include <hip/hip_runtime.h>
#include <stdint.h>

typedef unsigned short u16;
typedef __bf16 bf16x8 __attribute__((ext_vector_type(8)));
typedef float  f32x4  __attribute__((ext_vector_type(4)));

#define B_  2
#define T_  1024
#define C_  2048
#define H_  16
#define D_  128
#define NTENS 4194304   // elements in x and in each W (2*1024*2048 == 2048*2048)

// Native bf16 convert (RNE): compiler emits v_cvt_pk_bf16_f32; the old
// bit-math version cost 4 VALU ops per value (flash is VALU-bound).
__device__ __forceinline__ u16 f2bf(float f) {
    union { __bf16 h; u16 u; } v; v.h = (__bf16)f;
    return v.u;
}
__device__ __forceinline__ float bf2f(u16 h) {
    union { uint32_t u; float f; } v; v.u = ((uint32_t)h) << 16;
    return v.f;
}

// ---------------------------------------------------------------------------
// fp32 -> bf16 conversion; z in [0,5): {x,Wq,Wk,Wv,Wo}. z==5: RoPE table
// (first 64 blocks only) — folded here to save a launch.
// ---------------------------------------------------------------------------
__global__ __launch_bounds__(256) void k_convert(
    const float* __restrict__ x, const float* __restrict__ wq,
    const float* __restrict__ wk, const float* __restrict__ wv,
    const float* __restrict__ wo, u16* __restrict__ dst,
    float* __restrict__ ct, float* __restrict__ st)
{
    int z = blockIdx.z;
    if (z == 5) {
        int idx = blockIdx.x * 256 + threadIdx.x;
        if (idx < 65536) {
            int t = idx >> 6, d = idx & 63;
            float inv = expf(-(float)d * (9.210340371976184f / 64.0f));
            float th = (float)t * inv;
            float s, c;
            sincosf(th, &s, &c);
            ct[idx] = c;
            st[idx] = s;
        }
        return;
    }
    const float* src = (z == 0) ? x : (z == 1) ? wq : (z == 2) ? wk : (z == 3) ? wv : wo;
    u16* d = dst + (size_t)z * NTENS;
    size_t i = ((size_t)blockIdx.x * 256 + threadIdx.x) * 4;
    float4 v = *(const float4*)(src + i);
    ushort4 o;
    o.x = f2bf(v.x); o.y = f2bf(v.y); o.z = f2bf(v.z); o.w = f2bf(v.w);
    *(ushort4*)(d + i) = o;
}

// ---------------------------------------------------------------------------
// NT-form MTILE x 128 MFMA tile GEMM with async global->LDS staging.
// XOR-swizzled LDS (zero bank conflicts). Waves 1x4; wave w owns cols
// {16w..16w+15} and {64+16w..+15} so the RoPE pair (d,d+64) is in-lane.
// MTILE=64 @ 6 blk/CU is the verified optimum for THIS problem size and
// 2-barrier structure (rounds 1 & 3: both 128-row variants -> 92-96us;
// occupancy halves at 3 blk/CU and the barrier drain is no longer hidden).
// EPI: 0 = fp32 store, 1 = bf16 store, 2 = QKV epilogue:
//   z<2  -> RoPE in registers, bf16 store [t][c]
//   z==2 -> V with FUSED TRANSPOSE: store bf16 to vt [bh][d][t] directly
//           (tile n-range == one head since D==128; acc[i][j][0..3] are 4
//            consecutive tokens at fixed d -> contiguous ushort4 in [d][t])
// ---------------------------------------------------------------------------
template<int MTILE, int EPI>
__device__ __forceinline__ void gemm_tile_nt(
    const u16* __restrict__ A, int lda,
    const u16* __restrict__ Bp, int ldb,
    void* __restrict__ Cp, int ldc,
    int m0, int n0, int K,
    u16* SMEM, const float* __restrict__ ct, const float* __restrict__ st, int z)
{
    constexpr int MF  = MTILE / 16;
    constexpr int ACH = MTILE / 32;
    u16* As = SMEM;
    u16* Bs = SMEM + MTILE * 64;

    const int tid  = threadIdx.x;
    const int wave = tid >> 6;
    const int lane = tid & 63;
    const int frow = lane & 15;
    const int quad = lane >> 4;

    const int lrow8  = lane >> 3;
    const int slot   = lane & 7;
    const int gchunk = slot ^ lrow8;

    f32x4 acc[MF][2] = {};

    size_t aoff[ACH], boff[4];
#pragma unroll
    for (int i = 0; i < ACH; ++i) {
        int c = (i << 2) + wave;
        int r = (c << 3) + lrow8;
        aoff[i] = (size_t)(m0 + r) * lda + (gchunk << 3);
    }
#pragma unroll
    for (int i = 0; i < 4; ++i) {
        int r = (i << 5) + (wave << 3) + lrow8;
        boff[i] = (size_t)(n0 + r) * ldb + (gchunk << 3);
    }

    for (int kt = 0; kt < K; kt += 64) {
#pragma unroll
        for (int i = 0; i < ACH; ++i) {
            int c = (i << 2) + wave;
            __builtin_amdgcn_global_load_lds(
                (const __attribute__((address_space(1))) void*)(A + aoff[i] + kt),
                (__attribute__((address_space(3))) void*)(As + (c << 9)), 16, 0, 0);
        }
#pragma unroll
        for (int i = 0; i < 4; ++i) {
            int c = (i << 2) + wave;
            __builtin_amdgcn_global_load_lds(
                (const __attribute__((address_space(1))) void*)(Bp + boff[i] + kt),
                (__attribute__((address_space(3))) void*)(Bs + (c << 9)), 16, 0, 0);
        }
        __syncthreads();

#pragma unroll
        for (int ks = 0; ks < 2; ++ks) {
            int lk = (ks << 2) + quad;
            bf16x8 af[MF], bfv[2];
#pragma unroll
            for (int i = 0; i < MF; ++i) {
                int ar = (i << 4) + frow;
                af[i] = *(const bf16x8*)&As[ar * 64 + ((lk ^ (frow & 7)) << 3)];
            }
#pragma unroll
            for (int j = 0; j < 2; ++j) {
                int br = (wave << 4) + (j << 6) + frow;
                bfv[j] = *(const bf16x8*)&Bs[br * 64 + ((lk ^ (frow & 7)) << 3)];
            }
#pragma unroll
            for (int i = 0; i < MF; ++i)
#pragma unroll
                for (int j = 0; j < 2; ++j)
                    acc[i][j] = __builtin_amdgcn_mfma_f32_16x16x32_bf16(
                        af[i], bfv[j], acc[i][j], 0, 0, 0);
        }
        __syncthreads();
    }

    if constexpr (EPI == 2) {
        if (z < 2) {
            const int d = (wave << 4) + frow;
            const float sc = (z == 0) ? 0.08838834764831845f : 1.0f;
            u16* Op = (u16*)Cp;
#pragma unroll
            for (int i = 0; i < MF; ++i)
#pragma unroll
                for (int r = 0; r < 4; ++r) {
                    int m = m0 + (i << 4) + (quad << 2) + r;
                    int t = m & 1023;
                    float c = ct[t * 64 + d], s = st[t * 64 + d];
                    float a = acc[i][0][r], bb = acc[i][1][r];
                    Op[(size_t)m * ldc + n0 + d]      = f2bf((a * c - bb * s) * sc);
                    Op[(size_t)m * ldc + n0 + d + 64] = f2bf((bb * c + a * s) * sc);
                }
            return;
        }
        // z == 2: V with fused transpose. Cp is vt [bh][d][t]; this tile's
        // n-range [n0, n0+128) is exactly head h = n0>>7.
        const int hh = n0 >> 7;
        const int bI = m0 >> 10;
        const int t0 = m0 & 1023;
        u16* Vp = (u16*)Cp + ((size_t)((bI << 4) + hh)) * (D_ * T_);
#pragma unroll
        for (int i = 0; i < MF; ++i)
#pragma unroll
            for (int j = 0; j < 2; ++j) {
                int d = (wave << 4) + (j << 6) + frow;
                int t = t0 + (i << 4) + (quad << 2);
                ushort4 o;
                o.x = f2bf(acc[i][j][0]); o.y = f2bf(acc[i][j][1]);
                o.z = f2bf(acc[i][j][2]); o.w = f2bf(acc[i][j][3]);
                *(ushort4*)&Vp[(size_t)d * T_ + t] = o;
            }
        return;
    }

#pragma unroll
    for (int i = 0; i < MF; ++i)
#pragma unroll
        for (int j = 0; j < 2; ++j)
#pragma unroll
            for (int r = 0; r < 4; ++r) {
                int m = m0 + (i << 4) + (quad << 2) + r;
                int n = n0 + (wave << 4) + (j << 6) + frow;
                if constexpr (EPI == 0)
                    ((float*)Cp)[(size_t)m * ldc + n] = acc[i][j][r];
                else
                    ((u16*)Cp)[(size_t)m * ldc + n] = f2bf(acc[i][j][r]);
            }
}

// ---------------------------------------------------------------------------
// QKV projection with in-register RoPE epilogue (Q/K) and fused V transpose
// to [bh][d][t]. 64x128 tiles, grid (16,32,3) = 1536 blocks = 6 blk/CU.
// ---------------------------------------------------------------------------
__global__ __launch_bounds__(256) void k_gemm_qkv(
    const u16* __restrict__ xb, const u16* __restrict__ wq,
    const u16* __restrict__ wk, const u16* __restrict__ wv,
    u16* __restrict__ q, u16* __restrict__ k, u16* __restrict__ vt,
    const float* __restrict__ ct, const float* __restrict__ st)
{
    __shared__ u16 SMEM[64 * 64 + 128 * 64];
    int z = blockIdx.z;
    const u16* Bp = (z == 0) ? wq : (z == 1) ? wk : wv;
    u16* Op       = (z == 0) ? q  : (z == 1) ? k  : vt;
    gemm_tile_nt<64, 2>(xb, C_, Bp, C_, Op, C_,
                        blockIdx.y * 64, blockIdx.x * 128, C_, SMEM, ct, st, z);
}

// ---------------------------------------------------------------------------
// Fused flash attention v3: KV-tile 128, Q in registers, BOTH K and V^T
// staged with global_load_lds (V produced pre-transposed by the QKV GEMM
// epilogue). Grid 512, LPT pairing (pairs sum 9).
// LDS 64 KB: Ks[128x128] (reused as P, stride 136), Vs[128x128] ([d][tok]).
// T5: setprio(1) around both MFMA clusters (2 blk/CU, waves at independent
// phases -> scheduler has something to arbitrate; +4-7% measured on attn).
// ---------------------------------------------------------------------------
__global__ __launch_bounds__(256) void k_flash(
    const u16* __restrict__ qb, const u16* __restrict__ kb,
    const u16* __restrict__ vt, u16* __restrict__ yb)
{
    __shared__ u16 Ks[128 * 128];   // [tok][d]; P (stride 136) reuses this
    __shared__ u16 Vs[128 * 128];   // [d][tok]

    const int bx  = blockIdx.x;
    const int bh  = bx & 31, b = bh >> 4, h = bh & 15;
    const int qt  = (bx < 256) ? (15 - (bx >> 5)) : ((bx >> 5) - 8);
    const int KT  = (qt >> 1) + 1;
    const int tid = threadIdx.x, wave = tid >> 6, lane = tid & 63;
    const int frow = lane & 15, quad = lane >> 4;

    const u16* qbase = qb + (size_t)b * (T_ * C_) + h * D_;
    const u16* kbase = kb + (size_t)b * (T_ * C_) + h * D_;
    const u16* vbase = vt + (size_t)bh * (D_ * T_);
    const int q0 = qt << 6;

    // ---- Q fragments in registers (wave w owns q-rows q0+16w..+15) ----
    bf16x8 qf[4];
#pragma unroll
    for (int ks = 0; ks < 4; ++ks)
        qf[ks] = *(const bf16x8*)&qbase[(size_t)(q0 + (wave << 4) + frow) * C_
                                        + (ks << 5) + (quad << 3)];

    f32x4 Y[8] = {};
    float mrow[4], lrow[4];
#pragma unroll
    for (int r = 0; r < 4; ++r) { mrow[r] = -3e38f; lrow[r] = 0.f; }

    const int tok = q0 + (wave << 4) + (quad << 2);  // + r = global q row

    for (int kt = 0; kt < KT; ++kt) {
        const int k0 = kt << 7;
        // ---- stage K tile (128 tok x 128 d) and V^T tile (128 d x 128 tok) ----
        {
            const int r4 = lane >> 4, s16 = lane & 15;
#pragma unroll
            for (int i = 0; i < 8; ++i) {
                int c = (i << 2) + wave;             // 0..31, 4 rows each
                int row = (c << 2) + r4;             // 0..127
                int g = (s16 & 8) | ((s16 & 7) ^ (row & 7));
                __builtin_amdgcn_global_load_lds(
                    (const __attribute__((address_space(1))) void*)(kbase + (size_t)(k0 + row) * C_ + (g << 3)),
                    (__attribute__((address_space(3))) void*)(Ks + (c << 9)), 16, 0, 0);
                __builtin_amdgcn_global_load_lds(
                    (const __attribute__((address_space(1))) void*)(vbase + (size_t)row * T_ + k0 + (g << 3)),
                    (__attribute__((address_space(3))) void*)(Vs + (c << 9)), 16, 0, 0);
            }
        }
        __syncthreads();   // B1: tiles staged

        // ---- S = q K^T  (wave-tile 16 x 128) ----
        f32x4 S[8] = {};
        __builtin_amdgcn_s_setprio(1);
#pragma unroll
        for (int ks = 0; ks < 4; ++ks) {
            int lk = (ks << 2) + quad;
            int sw = ((lk & 8) | ((lk & 7) ^ (frow & 7))) << 3;
#pragma unroll
            for (int jj = 0; jj < 8; ++jj) {
                bf16x8 bb = *(const bf16x8*)&Ks[((jj << 4) + frow) * 128 + sw];
                S[jj] = __builtin_amdgcn_mfma_f32_16x16x32_bf16(qf[ks], bb, S[jj], 0, 0, 0);
            }
        }
        __builtin_amdgcn_s_setprio(0);

        // ---- causal mask (only the last kv-tile intersects the diagonal) ----
        if (kt == KT - 1) {
#pragma unroll
            for (int jj = 0; jj < 8; ++jj) {
                int colg = k0 + (jj << 4) + frow;
#pragma unroll
                for (int r = 0; r < 4; ++r)
                    if (colg > tok + r) S[jj][r] = -1e30f;
            }
        }

        // ---- online softmax (rows live in 16-lane frow groups) ----
        float al[4];
#pragma unroll
        for (int r = 0; r < 4; ++r) {
            float tm = -3e38f;
#pragma unroll
            for (int jj = 0; jj < 8; ++jj) tm = fmaxf(tm, S[jj][r]);
#pragma unroll
            for (int off = 8; off > 0; off >>= 1) tm = fmaxf(tm, __shfl_xor(tm, off));
            float mn = fmaxf(mrow[r], tm);
            al[r] = __expf(mrow[r] - mn);
            mrow[r] = mn;
            float rs = 0.f;
#pragma unroll
            for (int jj = 0; jj < 8; ++jj) {
                float e = __expf(S[jj][r] - mn);
                S[jj][r] = e;
                rs += e;
            }
#pragma unroll
            for (int off = 8; off > 0; off >>= 1) rs += __shfl_xor(rs, off);
            lrow[r] = lrow[r] * al[r] + rs;
        }
#pragma unroll
        for (int dj = 0; dj < 8; ++dj)
#pragma unroll
            for (int r = 0; r < 4; ++r) Y[dj][r] *= al[r];

        __syncthreads();   // B2: Ks reads done -> safe to overwrite with P

        // ---- write P into Ks region (A-layout, stride 136) ----
        u16* Ps = Ks;
#pragma unroll
        for (int jj = 0; jj < 8; ++jj)
#pragma unroll
            for (int r = 0; r < 4; ++r)
                Ps[((wave << 4) + (quad << 2) + r) * 136 + (jj << 4) + frow] = f2bf(S[jj][r]);

        // ---- Y += P V ----
        __builtin_amdgcn_s_setprio(1);
#pragma unroll
        for (int ks = 0; ks < 4; ++ks) {
            bf16x8 pa = *(const bf16x8*)&Ps[((wave << 4) + frow) * 136 + (ks << 5) + (quad << 3)];
            int lk = (ks << 2) + quad;
            int sw = ((lk & 8) | ((lk & 7) ^ (frow & 7))) << 3;
#pragma unroll
            for (int dj = 0; dj < 8; ++dj) {
                bf16x8 vv = *(const bf16x8*)&Vs[((dj << 4) + frow) * 128 + sw];
                Y[dj] = __builtin_amdgcn_mfma_f32_16x16x32_bf16(pa, vv, Y[dj], 0, 0, 0);
            }
        }
        __builtin_amdgcn_s_setprio(0);
        __syncthreads();   // B3: PV reads done before next-iter staging
    }

    // ---- epilogue: Y /= l, store to yb [b,t,h,d] ----
    u16* ybase = yb + (size_t)b * (T_ * C_) + h * D_;
#pragma unroll
    for (int r = 0; r < 4; ++r) {
        float inv = 1.0f / lrow[r];
#pragma unroll
        for (int dj = 0; dj < 8; ++dj)
            ybase[(size_t)(tok + r) * C_ + (dj << 4) + frow] = f2bf(Y[dj][r] * inv);
    }
}

// ---------------------------------------------------------------------------
// out = y @ Wo^T, fp32 output. 64x128 tile, grid (16,32) = 512 blocks = 2/CU.
// ---------------------------------------------------------------------------
__global__ __launch_bounds__(256) void k_gemm_out(
    const u16* __restrict__ yb, const u16* __restrict__ wo, float* __restrict__ out)
{
    __shared__ u16 SMEM[64 * 64 + 128 * 64];
    gemm_tile_nt<64, 0>(yb, C_, wo, C_, out, C_,
                        blockIdx.y * 64, blockIdx.x * 128, C_, SMEM, nullptr, nullptr, 0);
}

// ---------------------------------------------------------------------------
extern "C" void kernel_launch(void* const* d_in, const int* in_sizes, int n_in,
                              void* d_out, int out_size, void* d_ws, size_t ws_size,
                              hipStream_t stream)
{
    (void)in_sizes; (void)n_in; (void)out_size; (void)ws_size;
    const float* x  = (const float*)d_in[0];
    const float* Wq = (const float*)d_in[1];
    const float* Wk = (const float*)d_in[2];
    const float* Wv = (const float*)d_in[3];
    const float* Wo = (const float*)d_in[4];

    u16* ws  = (u16*)d_ws;
    u16* xb  = ws;
    u16* wqb = ws + (size_t)1 * NTENS;
    u16* wkb = ws + (size_t)2 * NTENS;
    u16* wvb = ws + (size_t)3 * NTENS;
    u16* wob = ws + (size_t)4 * NTENS;
    u16* qb  = ws + (size_t)5 * NTENS;
    u16* kb  = ws + (size_t)6 * NTENS;
    // slot 7 (vb) unused since V is written pre-transposed by the QKV GEMM
    u16* yb  = ws + (size_t)8 * NTENS;
    u16* vt  = ws + (size_t)9 * NTENS;         // [bh][d][t]
    float* ct = (float*)(ws + (size_t)10 * NTENS);
    float* st = ct + 65536;

    k_convert <<<dim3(4096, 1, 6), 256, 0, stream>>>(x, Wq, Wk, Wv, Wo, ws, ct, st);
    k_gemm_qkv<<<dim3(16, 32, 3), 256, 0, stream>>>(xb, wqb, wkb, wvb, qb, kb, vt, ct, st);
    k_flash   <<<dim3(512), 256, 0, stream>>>(qb, kb, vt, yb);
    k_gemm_out<<<dim3(16, 32, 1), 256, 0, stream>>>(yb, wob, (float*)d_out);
}

// Round 6
// 238.714 us; speedup vs baseline: 1.1371x; 1.0758x over previous
//
#include <hip/hip_runtime.h>
#include <stdint.h>

typedef unsigned short u16;
typedef __bf16 bf16x8 __attribute__((ext_vector_type(8)));
typedef float  f32x4  __attribute__((ext_vector_type(4)));

#define B_  2
#define T_  1024
#define C_  2048
#define H_  16
#define D_  128
#define NTENS 4194304   // elements in x and in each W (2*1024*2048 == 2048*2048)

__device__ __forceinline__ u16 f2bf(float f) {
    union { float f; uint32_t u; } v; v.f = f;
    uint32_t r = (v.u + 0x7FFFu + ((v.u >> 16) & 1u)) >> 16;
    return (u16)r;
}
__device__ __forceinline__ float bf2f(u16 h) {
    union { uint32_t u; float f; } v; v.u = ((uint32_t)h) << 16;
    return v.f;
}
// 2^x via v_exp_f32 (hardware exp IS base-2). __exp2f collides with a glibc
// math.h macro on this toolchain; the amdgcn builtin has no such collision.
__device__ __forceinline__ float fexp2(float x) {
    return __builtin_amdgcn_exp2f(x);
}

// ---------------------------------------------------------------------------
// fp32 -> bf16 conversion; z in [0,5): {x,Wq,Wk,Wv,Wo}. z==5: RoPE table
// (first 64 blocks only) — folded here to save a launch.
// ---------------------------------------------------------------------------
__global__ __launch_bounds__(256) void k_convert(
    const float* __restrict__ x, const float* __restrict__ wq,
    const float* __restrict__ wk, const float* __restrict__ wv,
    const float* __restrict__ wo, u16* __restrict__ dst,
    float* __restrict__ ct, float* __restrict__ st)
{
    int z = blockIdx.z;
    if (z == 5) {
        int idx = blockIdx.x * 256 + threadIdx.x;
        if (idx < 65536) {
            int t = idx >> 6, d = idx & 63;
            float inv = expf(-(float)d * (9.210340371976184f / 64.0f));
            float th = (float)t * inv;
            float s, c;
            sincosf(th, &s, &c);
            ct[idx] = c;
            st[idx] = s;
        }
        return;
    }
    const float* src = (z == 0) ? x : (z == 1) ? wq : (z == 2) ? wk : (z == 3) ? wv : wo;
    u16* d = dst + (size_t)z * NTENS;
    size_t i = ((size_t)blockIdx.x * 256 + threadIdx.x) * 4;
    float4 v = *(const float4*)(src + i);
    ushort4 o;
    o.x = f2bf(v.x); o.y = f2bf(v.y); o.z = f2bf(v.z); o.w = f2bf(v.w);
    *(ushort4*)(d + i) = o;
}

// ---------------------------------------------------------------------------
// NT-form MTILE x 128 MFMA tile GEMM with async global->LDS staging.
// XOR-swizzled LDS (zero bank conflicts). Waves 1x4; wave w owns cols
// {16w..16w+15} and {64+16w..+15} so the RoPE pair (d,d+64) is in-lane.
// MTILE=64 @ 6 blk/CU is the verified optimum for THIS problem size and
// 2-barrier structure (rounds 1 & 3: both 128-row variants -> 92-96us;
// occupancy halves at 3 blk/CU and the barrier drain is no longer hidden).
// EPI: 0 = fp32 store, 1 = bf16 store, 2 = QKV epilogue:
//   z<2  -> RoPE in registers, bf16 store [t][c].  NOTE: Q's scale folds in
//           log2(e) so flash softmax can use exp2 (v_exp_f32 IS 2^x):
//           0.08838834764831845 * 1.4426950408889634 = 0.12751743368.
//           Softmax is base-invariant, so output is unchanged.
//   z==2 -> V with FUSED TRANSPOSE: store bf16 to vt [bh][d][t] directly
//           (tile n-range == one head since D==128; acc[i][j][0..3] are 4
//            consecutive tokens at fixed d -> contiguous ushort4 in [d][t])
// ---------------------------------------------------------------------------
template<int MTILE, int EPI>
__device__ __forceinline__ void gemm_tile_nt(
    const u16* __restrict__ A, int lda,
    const u16* __restrict__ Bp, int ldb,
    void* __restrict__ Cp, int ldc,
    int m0, int n0, int K,
    u16* SMEM, const float* __restrict__ ct, const float* __restrict__ st, int z)
{
    constexpr int MF  = MTILE / 16;
    constexpr int ACH = MTILE / 32;
    u16* As = SMEM;
    u16* Bs = SMEM + MTILE * 64;

    const int tid  = threadIdx.x;
    const int wave = tid >> 6;
    const int lane = tid & 63;
    const int frow = lane & 15;
    const int quad = lane >> 4;

    const int lrow8  = lane >> 3;
    const int slot   = lane & 7;
    const int gchunk = slot ^ lrow8;

    f32x4 acc[MF][2] = {};

    size_t aoff[ACH], boff[4];
#pragma unroll
    for (int i = 0; i < ACH; ++i) {
        int c = (i << 2) + wave;
        int r = (c << 3) + lrow8;
        aoff[i] = (size_t)(m0 + r) * lda + (gchunk << 3);
    }
#pragma unroll
    for (int i = 0; i < 4; ++i) {
        int r = (i << 5) + (wave << 3) + lrow8;
        boff[i] = (size_t)(n0 + r) * ldb + (gchunk << 3);
    }

    for (int kt = 0; kt < K; kt += 64) {
#pragma unroll
        for (int i = 0; i < ACH; ++i) {
            int c = (i << 2) + wave;
            __builtin_amdgcn_global_load_lds(
                (const __attribute__((address_space(1))) void*)(A + aoff[i] + kt),
                (__attribute__((address_space(3))) void*)(As + (c << 9)), 16, 0, 0);
        }
#pragma unroll
        for (int i = 0; i < 4; ++i) {
            int c = (i << 2) + wave;
            __builtin_amdgcn_global_load_lds(
                (const __attribute__((address_space(1))) void*)(Bp + boff[i] + kt),
                (__attribute__((address_space(3))) void*)(Bs + (c << 9)), 16, 0, 0);
        }
        __syncthreads();

#pragma unroll
        for (int ks = 0; ks < 2; ++ks) {
            int lk = (ks << 2) + quad;
            bf16x8 af[MF], bfv[2];
#pragma unroll
            for (int i = 0; i < MF; ++i) {
                int ar = (i << 4) + frow;
                af[i] = *(const bf16x8*)&As[ar * 64 + ((lk ^ (frow & 7)) << 3)];
            }
#pragma unroll
            for (int j = 0; j < 2; ++j) {
                int br = (wave << 4) + (j << 6) + frow;
                bfv[j] = *(const bf16x8*)&Bs[br * 64 + ((lk ^ (frow & 7)) << 3)];
            }
#pragma unroll
            for (int i = 0; i < MF; ++i)
#pragma unroll
                for (int j = 0; j < 2; ++j)
                    acc[i][j] = __builtin_amdgcn_mfma_f32_16x16x32_bf16(
                        af[i], bfv[j], acc[i][j], 0, 0, 0);
        }
        __syncthreads();
    }

    if constexpr (EPI == 2) {
        if (z < 2) {
            const int d = (wave << 4) + frow;
            // z==0 (Q): 1/sqrt(128) * log2(e)  — see header comment.
            const float sc = (z == 0) ? 0.12751743368f : 1.0f;
            u16* Op = (u16*)Cp;
#pragma unroll
            for (int i = 0; i < MF; ++i)
#pragma unroll
                for (int r = 0; r < 4; ++r) {
                    int m = m0 + (i << 4) + (quad << 2) + r;
                    int t = m & 1023;
                    float c = ct[t * 64 + d], s = st[t * 64 + d];
                    float a = acc[i][0][r], bb = acc[i][1][r];
                    Op[(size_t)m * ldc + n0 + d]      = f2bf((a * c - bb * s) * sc);
                    Op[(size_t)m * ldc + n0 + d + 64] = f2bf((bb * c + a * s) * sc);
                }
            return;
        }
        // z == 2: V with fused transpose. Cp is vt [bh][d][t]; this tile's
        // n-range [n0, n0+128) is exactly head h = n0>>7.
        const int hh = n0 >> 7;
        const int bI = m0 >> 10;
        const int t0 = m0 & 1023;
        u16* Vp = (u16*)Cp + ((size_t)((bI << 4) + hh)) * (D_ * T_);
#pragma unroll
        for (int i = 0; i < MF; ++i)
#pragma unroll
            for (int j = 0; j < 2; ++j) {
                int d = (wave << 4) + (j << 6) + frow;
                int t = t0 + (i << 4) + (quad << 2);
                ushort4 o;
                o.x = f2bf(acc[i][j][0]); o.y = f2bf(acc[i][j][1]);
                o.z = f2bf(acc[i][j][2]); o.w = f2bf(acc[i][j][3]);
                *(ushort4*)&Vp[(size_t)d * T_ + t] = o;
            }
        return;
    }

#pragma unroll
    for (int i = 0; i < MF; ++i)
#pragma unroll
        for (int j = 0; j < 2; ++j)
#pragma unroll
            for (int r = 0; r < 4; ++r) {
                int m = m0 + (i << 4) + (quad << 2) + r;
                int n = n0 + (wave << 4) + (j << 6) + frow;
                if constexpr (EPI == 0)
                    ((float*)Cp)[(size_t)m * ldc + n] = acc[i][j][r];
                else
                    ((u16*)Cp)[(size_t)m * ldc + n] = f2bf(acc[i][j][r]);
            }
}

// ---------------------------------------------------------------------------
// QKV projection with in-register RoPE epilogue (Q/K) and fused V transpose
// to [bh][d][t]. 64x128 tiles, grid (16,32,3) = 1536 blocks = 6 blk/CU.
// ---------------------------------------------------------------------------
__global__ __launch_bounds__(256) void k_gemm_qkv(
    const u16* __restrict__ xb, const u16* __restrict__ wq,
    const u16* __restrict__ wk, const u16* __restrict__ wv,
    u16* __restrict__ q, u16* __restrict__ k, u16* __restrict__ vt,
    const float* __restrict__ ct, const float* __restrict__ st)
{
    __shared__ u16 SMEM[64 * 64 + 128 * 64];
    int z = blockIdx.z;
    const u16* Bp = (z == 0) ? wq : (z == 1) ? wk : wv;
    u16* Op       = (z == 0) ? q  : (z == 1) ? k  : vt;
    gemm_tile_nt<64, 2>(xb, C_, Bp, C_, Op, C_,
                        blockIdx.y * 64, blockIdx.x * 128, C_, SMEM, ct, st, z);
}

// ---------------------------------------------------------------------------
// Fused flash attention v3: KV-tile 128, Q in registers, BOTH K and V^T
// staged with global_load_lds (V produced pre-transposed by the QKV GEMM
// epilogue). Grid 512, LPT pairing (pairs sum 9).
// LDS 64 KB: Ks[128x128] (reused as P, stride 136), Vs[128x128] ([d][tok]).
// Split-wait staging: issue K loads then V loads; B1 waits only K
// (s_waitcnt vmcnt(8) + raw s_barrier) so V's memory latency hides under
// QK^T + softmax. B2's __syncthreads drains vmcnt(0) (compiler-guaranteed)
// before any wave reads Vs in PV, and before Ks is overwritten with P.
// Softmax runs in exp2 domain (Q pre-scaled by log2(e) in the projection).
// ---------------------------------------------------------------------------
__global__ __launch_bounds__(256) void k_flash(
    const u16* __restrict__ qb, const u16* __restrict__ kb,
    const u16* __restrict__ vt, u16* __restrict__ yb)
{
    __shared__ u16 Ks[128 * 128];   // [tok][d]; P (stride 136) reuses this
    __shared__ u16 Vs[128 * 128];   // [d][tok]

    const int bx  = blockIdx.x;
    const int bh  = bx & 31, b = bh >> 4, h = bh & 15;
    const int qt  = (bx < 256) ? (15 - (bx >> 5)) : ((bx >> 5) - 8);
    const int KT  = (qt >> 1) + 1;
    const int tid = threadIdx.x, wave = tid >> 6, lane = tid & 63;
    const int frow = lane & 15, quad = lane >> 4;

    const u16* qbase = qb + (size_t)b * (T_ * C_) + h * D_;
    const u16* kbase = kb + (size_t)b * (T_ * C_) + h * D_;
    const u16* vbase = vt + (size_t)bh * (D_ * T_);
    const int q0 = qt << 6;

    // ---- Q fragments in registers (wave w owns q-rows q0+16w..+15) ----
    bf16x8 qf[4];
#pragma unroll
    for (int ks = 0; ks < 4; ++ks)
        qf[ks] = *(const bf16x8*)&qbase[(size_t)(q0 + (wave << 4) + frow) * C_
                                        + (ks << 5) + (quad << 3)];

    f32x4 Y[8] = {};
    float mrow[4], lrow[4];
#pragma unroll
    for (int r = 0; r < 4; ++r) { mrow[r] = -3e38f; lrow[r] = 0.f; }

    const int tok = q0 + (wave << 4) + (quad << 2);  // + r = global q row

    for (int kt = 0; kt < KT; ++kt) {
        const int k0 = kt << 7;
        // ---- stage K tile (8 loads), then V^T tile (8 loads) ----
        {
            const int r4 = lane >> 4, s16 = lane & 15;
#pragma unroll
            for (int i = 0; i < 8; ++i) {
                int c = (i << 2) + wave;             // 0..31, 4 rows each
                int row = (c << 2) + r4;             // 0..127
                int g = (s16 & 8) | ((s16 & 7) ^ (row & 7));
                __builtin_amdgcn_global_load_lds(
                    (const __attribute__((address_space(1))) void*)(kbase + (size_t)(k0 + row) * C_ + (g << 3)),
                    (__attribute__((address_space(3))) void*)(Ks + (c << 9)), 16, 0, 0);
            }
#pragma unroll
            for (int i = 0; i < 8; ++i) {
                int c = (i << 2) + wave;
                int row = (c << 2) + r4;
                int g = (s16 & 8) | ((s16 & 7) ^ (row & 7));
                __builtin_amdgcn_global_load_lds(
                    (const __attribute__((address_space(1))) void*)(vbase + (size_t)row * T_ + k0 + (g << 3)),
                    (__attribute__((address_space(3))) void*)(Vs + (c << 9)), 16, 0, 0);
            }
        }
        // B1: wait own K loads only (8 V loads remain in flight), then
        // barrier -> all waves' K staged. sched_barrier fences ds_read
        // hoisting across the partial wait (rule #18).
        asm volatile("s_waitcnt vmcnt(8)" ::: "memory");
        __builtin_amdgcn_sched_barrier(0);
        __builtin_amdgcn_s_barrier();
        __builtin_amdgcn_sched_barrier(0);

        // ---- S = q K^T  (wave-tile 16 x 128) ----
        f32x4 S[8] = {};
#pragma unroll
        for (int ks = 0; ks < 4; ++ks) {
            int lk = (ks << 2) + quad;
            int sw = ((lk & 8) | ((lk & 7) ^ (frow & 7))) << 3;
#pragma unroll
            for (int jj = 0; jj < 8; ++jj) {
                bf16x8 bb = *(const bf16x8*)&Ks[((jj << 4) + frow) * 128 + sw];
                S[jj] = __builtin_amdgcn_mfma_f32_16x16x32_bf16(qf[ks], bb, S[jj], 0, 0, 0);
            }
        }

        // ---- causal mask (only the last kv-tile intersects the diagonal) ----
        if (kt == KT - 1) {
#pragma unroll
            for (int jj = 0; jj < 8; ++jj) {
                int colg = k0 + (jj << 4) + frow;
#pragma unroll
                for (int r = 0; r < 4; ++r)
                    if (colg > tok + r) S[jj][r] = -1e30f;
            }
        }

        // ---- online softmax in exp2 domain (rows in 16-lane frow groups) ----
        float al[4];
#pragma unroll
        for (int r = 0; r < 4; ++r) {
            float tm = -3e38f;
#pragma unroll
            for (int jj = 0; jj < 8; ++jj) tm = fmaxf(tm, S[jj][r]);
#pragma unroll
            for (int off = 8; off > 0; off >>= 1) tm = fmaxf(tm, __shfl_xor(tm, off));
            float mn = fmaxf(mrow[r], tm);
            al[r] = fexp2(mrow[r] - mn);
            mrow[r] = mn;
            float rs = 0.f;
#pragma unroll
            for (int jj = 0; jj < 8; ++jj) {
                float e = fexp2(S[jj][r] - mn);
                S[jj][r] = e;
                rs += e;
            }
#pragma unroll
            for (int off = 8; off > 0; off >>= 1) rs += __shfl_xor(rs, off);
            lrow[r] = lrow[r] * al[r] + rs;
        }
#pragma unroll
        for (int dj = 0; dj < 8; ++dj)
#pragma unroll
            for (int r = 0; r < 4; ++r) Y[dj][r] *= al[r];

        __syncthreads();   // B2: Ks reads done by all waves (safe to overwrite
                           // with P) AND vmcnt(0) drain -> Vs fully staged.

        // ---- write P into Ks region (A-layout, stride 136) ----
        u16* Ps = Ks;
#pragma unroll
        for (int jj = 0; jj < 8; ++jj)
#pragma unroll
            for (int r = 0; r < 4; ++r)
                Ps[((wave << 4) + (quad << 2) + r) * 136 + (jj << 4) + frow] = f2bf(S[jj][r]);

        // ---- Y += P V ----
#pragma unroll
        for (int ks = 0; ks < 4; ++ks) {
            bf16x8 pa = *(const bf16x8*)&Ps[((wave << 4) + frow) * 136 + (ks << 5) + (quad << 3)];
            int lk = (ks << 2) + quad;
            int sw = ((lk & 8) | ((lk & 7) ^ (frow & 7))) << 3;
#pragma unroll
            for (int dj = 0; dj < 8; ++dj) {
                bf16x8 vv = *(const bf16x8*)&Vs[((dj << 4) + frow) * 128 + sw];
                Y[dj] = __builtin_amdgcn_mfma_f32_16x16x32_bf16(pa, vv, Y[dj], 0, 0, 0);
            }
        }
        __syncthreads();   // B3: PV reads done before next-iter staging
    }

    // ---- epilogue: Y /= l, store to yb [b,t,h,d] ----
    u16* ybase = yb + (size_t)b * (T_ * C_) + h * D_;
#pragma unroll
    for (int r = 0; r < 4; ++r) {
        float inv = 1.0f / lrow[r];
#pragma unroll
        for (int dj = 0; dj < 8; ++dj)
            ybase[(size_t)(tok + r) * C_ + (dj << 4) + frow] = f2bf(Y[dj][r] * inv);
    }
}

// ---------------------------------------------------------------------------
// out = y @ Wo^T, fp32 output. 64x128 tile, grid (16,32) = 512 blocks = 2/CU.
// ---------------------------------------------------------------------------
__global__ __launch_bounds__(256) void k_gemm_out(
    const u16* __restrict__ yb, const u16* __restrict__ wo, float* __restrict__ out)
{
    __shared__ u16 SMEM[64 * 64 + 128 * 64];
    gemm_tile_nt<64, 0>(yb, C_, wo, C_, out, C_,
                        blockIdx.y * 64, blockIdx.x * 128, C_, SMEM, nullptr, nullptr, 0);
}

// ---------------------------------------------------------------------------
extern "C" void kernel_launch(void* const* d_in, const int* in_sizes, int n_in,
                              void* d_out, int out_size, void* d_ws, size_t ws_size,
                              hipStream_t stream)
{
    (void)in_sizes; (void)n_in; (void)out_size; (void)ws_size;
    const float* x  = (const float*)d_in[0];
    const float* Wq = (const float*)d_in[1];
    const float* Wk = (const float*)d_in[2];
    const float* Wv = (const float*)d_in[3];
    const float* Wo = (const float*)d_in[4];

    u16* ws  = (u16*)d_ws;
    u16* xb  = ws;
    u16* wqb = ws + (size_t)1 * NTENS;
    u16* wkb = ws + (size_t)2 * NTENS;
    u16* wvb = ws + (size_t)3 * NTENS;
    u16* wob = ws + (size_t)4 * NTENS;
    u16* qb  = ws + (size_t)5 * NTENS;
    u16* kb  = ws + (size_t)6 * NTENS;
    // slot 7 (vb) unused since V is written pre-transposed by the QKV GEMM
    u16* yb  = ws + (size_t)8 * NTENS;
    u16* vt  = ws + (size_t)9 * NTENS;         // [bh][d][t]
    float* ct = (float*)(ws + (size_t)10 * NTENS);
    float* st = ct + 65536;

    k_convert <<<dim3(4096, 1, 6), 256, 0, stream>>>(x, Wq, Wk, Wv, Wo, ws, ct, st);
    k_gemm_qkv<<<dim3(16, 32, 3), 256, 0, stream>>>(xb, wqb, wkb, wvb, qb, kb, vt, ct, st);
    k_flash   <<<dim3(512), 256, 0, stream>>>(qb, kb, vt, yb);
    k_gemm_out<<<dim3(16, 32, 1), 256, 0, stream>>>(yb, wob, (float*)d_out);
}